// Round 1
// baseline (420.038 us; speedup 1.0000x reference)
//
#include <hip/hip_runtime.h>
#include <hip/hip_bf16.h>

#define BB 4
#define CC_ 384
#define HH 32
#define WW 32
#define HWSZ 1024
#define NHD 12
#define HCH 32
#define GG 6
#define NGC_ 64
#define GHD 2
#define HK_ 16
#define WK_ 16
#define NS_ 256
#define RPEW 63
#define SCALE_ 0.17677669529663687f

// ---------------- K1/K4/K6: 1x1 conv / batched GEMM ----------------
// Y[b][o][n] = sum_c W[o][c] * X[b][c][n] + bias[o]
// grid: (1, OC/4, B), block: N/4 threads. Each thread: 4 o x 4 n (float4).
template<int CIN>
__global__ void conv1x1_kernel(const float* __restrict__ W, const float* __restrict__ bias,
                               const float* __restrict__ X, float* __restrict__ Y,
                               int N, int OC)
{
    const int otile = blockIdx.y * 4;
    const int b = blockIdx.z;
    const int n4 = (blockIdx.x * blockDim.x + threadIdx.x) * 4;
    const float* Xb = X + (size_t)b * CIN * N + n4;
    const float* Wr = W + (size_t)otile * CIN;

    float acc[4][4];
#pragma unroll
    for (int j = 0; j < 4; ++j)
#pragma unroll
        for (int i = 0; i < 4; ++i) acc[j][i] = 0.f;

    for (int c = 0; c < CIN; ++c) {
        float4 xv = *(const float4*)(Xb + (size_t)c * N);
#pragma unroll
        for (int j = 0; j < 4; ++j) {
            float w = Wr[j * CIN + c];   // uniform address -> scalar load
            acc[j][0] = fmaf(w, xv.x, acc[j][0]);
            acc[j][1] = fmaf(w, xv.y, acc[j][1]);
            acc[j][2] = fmaf(w, xv.z, acc[j][2]);
            acc[j][3] = fmaf(w, xv.w, acc[j][3]);
        }
    }
#pragma unroll
    for (int j = 0; j < 4; ++j) {
        int o = otile + j;
        float bv = bias[o];
        float4 r = make_float4(acc[j][0] + bv, acc[j][1] + bv, acc[j][2] + bv, acc[j][3] + bv);
        *(float4*)(Y + ((size_t)(b * OC + o)) * N + n4) = r;
    }
}

// ---------------- K2: offset network ----------------
// one block per bg (24 blocks), 256 threads = 16x16 output positions
__global__ void offset_net_kernel(const float* __restrict__ qb, const float* __restrict__ dww,
                                  const float* __restrict__ dwb, const float* __restrict__ lng,
                                  const float* __restrict__ lnb, const float* __restrict__ pww,
                                  float* __restrict__ posb)
{
    __shared__ float img[HWSZ];
    __shared__ float co[NGC_ * 256];
    const int bg = blockIdx.x;
    const int b = bg / GG, g = bg - b * GG;
    const int tid = threadIdx.x;
    const int oy = tid >> 4, ox = tid & 15;
    const float* qbase = qb + ((size_t)(b * CC_ + g * NGC_)) * HWSZ;

    for (int c = 0; c < NGC_; ++c) {
        __syncthreads();
        for (int e = tid; e < HWSZ; e += 256) img[e] = qbase[(size_t)c * HWSZ + e];
        __syncthreads();
        float s = dwb[c];
        const float* wf = dww + c * 25;
        const int iy0 = oy * 2 - 2, ix0 = ox * 2 - 2;
#pragma unroll
        for (int ky = 0; ky < 5; ++ky) {
            int iy = iy0 + ky;
            if (iy < 0 || iy > 31) continue;
#pragma unroll
            for (int kx = 0; kx < 5; ++kx) {
                int ix = ix0 + kx;
                if (ix < 0 || ix > 31) continue;
                s = fmaf(img[iy * 32 + ix], wf[ky * 5 + kx], s);
            }
        }
        co[c * 256 + tid] = s;
    }
    // channel LayerNorm (per spatial position) — thread-private column
    float mu = 0.f;
    for (int c = 0; c < NGC_; ++c) mu += co[c * 256 + tid];
    mu *= (1.f / 64.f);
    float var = 0.f;
    for (int c = 0; c < NGC_; ++c) { float d = co[c * 256 + tid] - mu; var += d * d; }
    var *= (1.f / 64.f);
    float rstd = rsqrtf(var + 1e-5f);
    float o0 = 0.f, o1 = 0.f;
    for (int c = 0; c < NGC_; ++c) {
        float v = (co[c * 256 + tid] - mu) * rstd * lng[c] + lnb[c];
        float gv = 0.5f * v * (1.f + erff(v * 0.70710678118654752f));
        o0 = fmaf(pww[c], gv, o0);
        o1 = fmaf(pww[64 + c], gv, o1);
    }
    // tanh * 2/15 + reference grid (y,x)
    float py = tanhf(o0) * (2.f / 15.f) + ((0.5f + (float)oy) * (1.f / 15.f)) * 2.f - 1.f;
    float px = tanhf(o1) * (2.f / 15.f) + ((0.5f + (float)ox) * (1.f / 15.f)) * 2.f - 1.f;
    posb[bg * 512 + tid * 2 + 0] = py;
    posb[bg * 512 + tid * 2 + 1] = px;
}

// ---------------- K3: bilinear KV sampling ----------------
// grid: (64 cc, 24 bg), block 256 = samples
__global__ void sample_xs_kernel(const float* __restrict__ x, const float* __restrict__ posb,
                                 float* __restrict__ xsb)
{
    const int cc = blockIdx.x, bg = blockIdx.y;
    const int b = bg / GG, g = bg - b * GG;
    const int s = threadIdx.x;
    float py = posb[bg * 512 + s * 2 + 0];
    float px = posb[bg * 512 + s * 2 + 1];
    float xi = (px + 1.f) * 0.5f * 31.f;
    float yi = (py + 1.f) * 0.5f * 31.f;
    float x0f = floorf(xi), y0f = floorf(yi);
    int x0 = (int)x0f, y0 = (int)y0f;
    float wx1 = xi - x0f, wy1 = yi - y0f;
    const float* img = x + ((size_t)(b * CC_ + g * NGC_ + cc)) * HWSZ;
    float acc = 0.f;
#pragma unroll
    for (int t = 0; t < 4; ++t) {
        int iy = y0 + (t >> 1), ix = x0 + (t & 1);
        float w = ((t >> 1) ? wy1 : 1.f - wy1) * ((t & 1) ? wx1 : 1.f - wx1);
        if (iy >= 0 && iy <= 31 && ix >= 0 && ix <= 31)
            acc = fmaf(img[iy * 32 + ix], w, acc);
    }
    xsb[((size_t)(b * CC_ + g * NGC_ + cc)) * NS_ + s] = acc;
}

// ---------------- K5: fused attention (logits + RPE bias + softmax + PV) ----------------
// grid: (4 qtiles, 48 bh), block 256 (one query per thread)
#define KSP 36
__launch_bounds__(256)
__global__ void attn_kernel(const float* __restrict__ qb, const float* __restrict__ kb,
                            const float* __restrict__ vb, const float* __restrict__ posb,
                            const float* __restrict__ rpe, float* __restrict__ ao)
{
    __shared__ float ks[256 * KSP];
    __shared__ float vs[256 * KSP];
    __shared__ float rp[RPEW * RPEW];
    __shared__ float ps[512];
    const int bh = blockIdx.y;
    const int b = bh / NHD, h = bh - b * NHD;
    const int bg = b * GG + (h >> 1);
    const int tid = threadIdx.x;

    const float* kg = kb + (size_t)bh * (HCH * NS_);
    const float* vg = vb + (size_t)bh * (HCH * NS_);
    for (int e = tid; e < HCH * NS_; e += 256) {
        int c = e >> 8, s = e & 255;
        ks[s * KSP + c] = kg[e];
        vs[s * KSP + c] = vg[e];
    }
    for (int e = tid; e < RPEW * RPEW; e += 256) rp[e] = rpe[(size_t)h * (RPEW * RPEW) + e];
    for (int e = tid; e < 512; e += 256) ps[e] = posb[bg * 512 + e];
    __syncthreads();

    const int qidx = blockIdx.x * 256 + tid;
    const int row = qidx >> 5, col = qidx & 31;
    const float gyq = (float)row * (2.f / 31.f) - 1.f;
    const float gxq = (float)col * (2.f / 31.f) - 1.f;

    float qf[32];
    const float* qg = qb + ((size_t)(b * CC_ + h * HCH)) * HWSZ + qidx;
#pragma unroll
    for (int c = 0; c < 32; ++c) qf[c] = qg[(size_t)c * HWSZ];

    float m = -3.0e38f, l = 0.f;
    float oacc[32];
#pragma unroll
    for (int c = 0; c < 32; ++c) oacc[c] = 0.f;

    for (int s = 0; s < NS_; ++s) {
        const float* kr = ks + s * KSP;
        float dot = 0.f;
#pragma unroll
        for (int c4 = 0; c4 < 8; ++c4) {
            float4 kv = *(const float4*)(kr + c4 * 4);
            dot = fmaf(qf[c4 * 4 + 0], kv.x, dot);
            dot = fmaf(qf[c4 * 4 + 1], kv.y, dot);
            dot = fmaf(qf[c4 * 4 + 2], kv.z, dot);
            dot = fmaf(qf[c4 * 4 + 3], kv.w, dot);
        }
        // RPE bias: bilinear sample of rp at displacement grid
        float py = ps[s * 2 + 0], px = ps[s * 2 + 1];
        float dy = (gyq - py) * 0.5f, dx = (gxq - px) * 0.5f;
        float yi = (dy + 1.f) * 31.f, xi = (dx + 1.f) * 31.f;
        float y0f = floorf(yi), x0f = floorf(xi);
        int y0 = (int)y0f, x0 = (int)x0f;
        float wy1 = yi - y0f, wx1 = xi - x0f;
        float bias = 0.f;
#pragma unroll
        for (int t = 0; t < 4; ++t) {
            int iy = y0 + (t >> 1), ix = x0 + (t & 1);
            float w = ((t >> 1) ? wy1 : 1.f - wy1) * ((t & 1) ? wx1 : 1.f - wx1);
            if (iy >= 0 && iy <= 62 && ix >= 0 && ix <= 62)
                bias = fmaf(rp[iy * 63 + ix], w, bias);
        }
        float logit = fmaf(dot, SCALE_, bias);
        // online softmax
        if (logit > m) {
            float corr = __expf(m - logit);
            l *= corr;
#pragma unroll
            for (int c = 0; c < 32; ++c) oacc[c] *= corr;
            m = logit;
        }
        float p = __expf(logit - m);
        l += p;
        const float* vr = vs + s * KSP;
#pragma unroll
        for (int c4 = 0; c4 < 8; ++c4) {
            float4 vv = *(const float4*)(vr + c4 * 4);
            oacc[c4 * 4 + 0] = fmaf(p, vv.x, oacc[c4 * 4 + 0]);
            oacc[c4 * 4 + 1] = fmaf(p, vv.y, oacc[c4 * 4 + 1]);
            oacc[c4 * 4 + 2] = fmaf(p, vv.z, oacc[c4 * 4 + 2]);
            oacc[c4 * 4 + 3] = fmaf(p, vv.w, oacc[c4 * 4 + 3]);
        }
    }
    float inv = 1.f / l;
    float* og = ao + ((size_t)(b * CC_ + h * HCH)) * HWSZ + qidx;
#pragma unroll
    for (int c = 0; c < 32; ++c) og[(size_t)c * HWSZ] = oacc[c] * inv;
}

extern "C" void kernel_launch(void* const* d_in, const int* in_sizes, int n_in,
                              void* d_out, int out_size, void* d_ws, size_t ws_size,
                              hipStream_t stream) {
    (void)in_sizes; (void)n_in; (void)out_size; (void)ws_size;
    const float* x   = (const float*)d_in[0];
    const float* Wq  = (const float*)d_in[1];
    const float* bq  = (const float*)d_in[2];
    const float* Wk  = (const float*)d_in[3];
    const float* bk  = (const float*)d_in[4];
    const float* Wv  = (const float*)d_in[5];
    const float* bv  = (const float*)d_in[6];
    const float* Wo  = (const float*)d_in[7];
    const float* bo  = (const float*)d_in[8];
    const float* dww = (const float*)d_in[9];
    const float* dwb = (const float*)d_in[10];
    const float* lng = (const float*)d_in[11];
    const float* lnb = (const float*)d_in[12];
    const float* pww = (const float*)d_in[13];
    const float* rpe = (const float*)d_in[14];
    float* out = (float*)d_out;

    float* ws   = (float*)d_ws;
    float* qbuf = ws;                       // 4*384*1024 = 1572864
    float* posb = qbuf + 1572864;           // 24*256*2   = 12288
    float* xsb  = posb + 12288;             // 4*384*256  = 393216
    float* kbuf = xsb + 393216;             // 393216
    float* vbuf = kbuf + 393216;            // 393216
    float* aout = vbuf + 393216;            // 1572864

    // K1: q = Wq x + bq
    conv1x1_kernel<CC_><<<dim3(1, CC_ / 4, BB), 256, 0, stream>>>(Wq, bq, x, qbuf, HWSZ, CC_);
    // K2: offset network -> pos
    offset_net_kernel<<<dim3(24), 256, 0, stream>>>(qbuf, dww, dwb, lng, lnb, pww, posb);
    // K3: deformable sampling -> xs
    sample_xs_kernel<<<dim3(NGC_, 24), 256, 0, stream>>>(x, posb, xsb);
    // K4: k, v projections
    conv1x1_kernel<CC_><<<dim3(1, CC_ / 4, BB), 64, 0, stream>>>(Wk, bk, xsb, kbuf, NS_, CC_);
    conv1x1_kernel<CC_><<<dim3(1, CC_ / 4, BB), 64, 0, stream>>>(Wv, bv, xsb, vbuf, NS_, CC_);
    // K5: fused attention
    attn_kernel<<<dim3(4, BB * NHD), 256, 0, stream>>>(qbuf, kbuf, vbuf, posb, rpe, aout);
    // K6: output projection
    conv1x1_kernel<CC_><<<dim3(1, CC_ / 4, BB), 256, 0, stream>>>(Wo, bo, aout, out, HWSZ, CC_);
}

// Round 2
// 341.852 us; speedup vs baseline: 1.2287x; 1.2287x over previous
//
#include <hip/hip_runtime.h>
#include <hip/hip_bf16.h>

#define BB 4
#define CC_ 384
#define HH 32
#define WW 32
#define HWSZ 1024
#define NHD 12
#define HCH 32
#define GG 6
#define NGC_ 64
#define GHD 2
#define HK_ 16
#define WK_ 16
#define NS_ 256
#define RPEW 63
#define SCALE_ 0.17677669529663687f

// ---------------- K1/K4/K6: 1x1 conv / batched GEMM ----------------
// Y[b][o][n] = sum_c W[o][c] * X[b][c][n] + bias[o]
// grid: (1, OC/4, B), block: N/4 threads. Each thread: 4 o x 4 n (float4).
template<int CIN>
__global__ void conv1x1_kernel(const float* __restrict__ W, const float* __restrict__ bias,
                               const float* __restrict__ X, float* __restrict__ Y,
                               int N, int OC)
{
    const int otile = blockIdx.y * 4;
    const int b = blockIdx.z;
    const int n4 = (blockIdx.x * blockDim.x + threadIdx.x) * 4;
    const float* Xb = X + (size_t)b * CIN * N + n4;
    const float* Wr = W + (size_t)otile * CIN;

    float acc[4][4];
#pragma unroll
    for (int j = 0; j < 4; ++j)
#pragma unroll
        for (int i = 0; i < 4; ++i) acc[j][i] = 0.f;

    for (int c = 0; c < CIN; ++c) {
        float4 xv = *(const float4*)(Xb + (size_t)c * N);
#pragma unroll
        for (int j = 0; j < 4; ++j) {
            float w = Wr[j * CIN + c];   // uniform address -> scalar load
            acc[j][0] = fmaf(w, xv.x, acc[j][0]);
            acc[j][1] = fmaf(w, xv.y, acc[j][1]);
            acc[j][2] = fmaf(w, xv.z, acc[j][2]);
            acc[j][3] = fmaf(w, xv.w, acc[j][3]);
        }
    }
#pragma unroll
    for (int j = 0; j < 4; ++j) {
        int o = otile + j;
        float bv = bias[o];
        float4 r = make_float4(acc[j][0] + bv, acc[j][1] + bv, acc[j][2] + bv, acc[j][3] + bv);
        *(float4*)(Y + ((size_t)(b * OC + o)) * N + n4) = r;
    }
}

// ---------------- K2: offset network ----------------
__global__ void offset_net_kernel(const float* __restrict__ qb, const float* __restrict__ dww,
                                  const float* __restrict__ dwb, const float* __restrict__ lng,
                                  const float* __restrict__ lnb, const float* __restrict__ pww,
                                  float* __restrict__ posb)
{
    __shared__ float img[HWSZ];
    __shared__ float co[NGC_ * 256];
    const int bg = blockIdx.x;
    const int b = bg / GG, g = bg - b * GG;
    const int tid = threadIdx.x;
    const int oy = tid >> 4, ox = tid & 15;
    const float* qbase = qb + ((size_t)(b * CC_ + g * NGC_)) * HWSZ;

    for (int c = 0; c < NGC_; ++c) {
        __syncthreads();
        for (int e = tid; e < HWSZ; e += 256) img[e] = qbase[(size_t)c * HWSZ + e];
        __syncthreads();
        float s = dwb[c];
        const float* wf = dww + c * 25;
        const int iy0 = oy * 2 - 2, ix0 = ox * 2 - 2;
#pragma unroll
        for (int ky = 0; ky < 5; ++ky) {
            int iy = iy0 + ky;
            if (iy < 0 || iy > 31) continue;
#pragma unroll
            for (int kx = 0; kx < 5; ++kx) {
                int ix = ix0 + kx;
                if (ix < 0 || ix > 31) continue;
                s = fmaf(img[iy * 32 + ix], wf[ky * 5 + kx], s);
            }
        }
        co[c * 256 + tid] = s;
    }
    float mu = 0.f;
    for (int c = 0; c < NGC_; ++c) mu += co[c * 256 + tid];
    mu *= (1.f / 64.f);
    float var = 0.f;
    for (int c = 0; c < NGC_; ++c) { float d = co[c * 256 + tid] - mu; var += d * d; }
    var *= (1.f / 64.f);
    float rstd = rsqrtf(var + 1e-5f);
    float o0 = 0.f, o1 = 0.f;
    for (int c = 0; c < NGC_; ++c) {
        float v = (co[c * 256 + tid] - mu) * rstd * lng[c] + lnb[c];
        float gv = 0.5f * v * (1.f + erff(v * 0.70710678118654752f));
        o0 = fmaf(pww[c], gv, o0);
        o1 = fmaf(pww[64 + c], gv, o1);
    }
    float py = tanhf(o0) * (2.f / 15.f) + ((0.5f + (float)oy) * (1.f / 15.f)) * 2.f - 1.f;
    float px = tanhf(o1) * (2.f / 15.f) + ((0.5f + (float)ox) * (1.f / 15.f)) * 2.f - 1.f;
    posb[bg * 512 + tid * 2 + 0] = py;
    posb[bg * 512 + tid * 2 + 1] = px;
}

// ---------------- K3: bilinear KV sampling ----------------
__global__ void sample_xs_kernel(const float* __restrict__ x, const float* __restrict__ posb,
                                 float* __restrict__ xsb)
{
    const int cc = blockIdx.x, bg = blockIdx.y;
    const int b = bg / GG, g = bg - b * GG;
    const int s = threadIdx.x;
    float py = posb[bg * 512 + s * 2 + 0];
    float px = posb[bg * 512 + s * 2 + 1];
    float xi = (px + 1.f) * 0.5f * 31.f;
    float yi = (py + 1.f) * 0.5f * 31.f;
    float x0f = floorf(xi), y0f = floorf(yi);
    int x0 = (int)x0f, y0 = (int)y0f;
    float wx1 = xi - x0f, wy1 = yi - y0f;
    const float* img = x + ((size_t)(b * CC_ + g * NGC_ + cc)) * HWSZ;
    float acc = 0.f;
#pragma unroll
    for (int t = 0; t < 4; ++t) {
        int iy = y0 + (t >> 1), ix = x0 + (t & 1);
        float w = ((t >> 1) ? wy1 : 1.f - wy1) * ((t & 1) ? wx1 : 1.f - wx1);
        if (iy >= 0 && iy <= 31 && ix >= 0 && ix <= 31)
            acc = fmaf(img[iy * 32 + ix], w, acc);
    }
    xsb[((size_t)(b * CC_ + g * NGC_ + cc)) * NS_ + s] = acc;
}

// ---------------- K5: fused attention, in-block sample-split ----------------
// grid: (4 qtiles, 48 bh), block 1024 = 4 wave-groups x 256 queries
// wave-group w handles samples [w*64, w*64+64); merge via LDS at the end.
#define KSP 36
__launch_bounds__(1024, 4)
__global__ void attn_kernel(const float* __restrict__ qb, const float* __restrict__ kb,
                            const float* __restrict__ vb, const float* __restrict__ posb,
                            const float* __restrict__ rpe, float* __restrict__ ao)
{
    __shared__ float ks[256 * KSP];
    __shared__ float vs[256 * KSP];
    __shared__ float rp[4096];      // 63*63 = 3969 used; reused as float4 redbuf[1024] in merge
    __shared__ float ps[512];
    __shared__ float ml[2048];      // m,l per thread
    const int bh = blockIdx.y;
    const int b = bh / NHD, h = bh - b * NHD;
    const int bg = b * GG + (h >> 1);
    const int tid = threadIdx.x;
    const int w = tid >> 8, t = tid & 255;

    const float* kg = kb + (size_t)bh * (HCH * NS_);
    const float* vg = vb + (size_t)bh * (HCH * NS_);
    for (int e = tid; e < HCH * NS_; e += 1024) {
        int c = e >> 8, s = e & 255;
        ks[s * KSP + c] = kg[e];
        vs[s * KSP + c] = vg[e];
    }
    for (int e = tid; e < RPEW * RPEW; e += 1024) rp[e] = rpe[(size_t)h * (RPEW * RPEW) + e];
    if (tid < 512) ps[tid] = posb[bg * 512 + tid];
    __syncthreads();

    const int qidx = blockIdx.x * 256 + t;
    const int row = qidx >> 5, col = qidx & 31;
    const float gyq = (float)row * (2.f / 31.f) - 1.f;
    const float gxq = (float)col * (2.f / 31.f) - 1.f;

    float qf[32];
    const float* qg = qb + ((size_t)(b * CC_ + h * HCH)) * HWSZ + qidx;
#pragma unroll
    for (int c = 0; c < 32; ++c) qf[c] = qg[(size_t)c * HWSZ];

    float m = -3.0e38f, l = 0.f;
    float oacc[32];
#pragma unroll
    for (int c = 0; c < 32; ++c) oacc[c] = 0.f;

    const int s0 = w * 64;
    for (int s = s0; s < s0 + 64; ++s) {
        const float* kr = ks + s * KSP;
        float d0 = 0.f, d1 = 0.f, d2 = 0.f, d3 = 0.f;
#pragma unroll
        for (int c4 = 0; c4 < 2; ++c4) {
            float4 ka = *(const float4*)(kr + c4 * 16 + 0);
            float4 kb4 = *(const float4*)(kr + c4 * 16 + 4);
            float4 kc = *(const float4*)(kr + c4 * 16 + 8);
            float4 kd = *(const float4*)(kr + c4 * 16 + 12);
            int o = c4 * 16;
            d0 = fmaf(qf[o + 0], ka.x, d0); d0 = fmaf(qf[o + 1], ka.y, d0);
            d0 = fmaf(qf[o + 2], ka.z, d0); d0 = fmaf(qf[o + 3], ka.w, d0);
            d1 = fmaf(qf[o + 4], kb4.x, d1); d1 = fmaf(qf[o + 5], kb4.y, d1);
            d1 = fmaf(qf[o + 6], kb4.z, d1); d1 = fmaf(qf[o + 7], kb4.w, d1);
            d2 = fmaf(qf[o + 8], kc.x, d2); d2 = fmaf(qf[o + 9], kc.y, d2);
            d2 = fmaf(qf[o + 10], kc.z, d2); d2 = fmaf(qf[o + 11], kc.w, d2);
            d3 = fmaf(qf[o + 12], kd.x, d3); d3 = fmaf(qf[o + 13], kd.y, d3);
            d3 = fmaf(qf[o + 14], kd.z, d3); d3 = fmaf(qf[o + 15], kd.w, d3);
        }
        float dot = (d0 + d1) + (d2 + d3);

        float py = ps[s * 2 + 0], px = ps[s * 2 + 1];
        float dy = (gyq - py) * 0.5f, dx = (gxq - px) * 0.5f;
        float yi = (dy + 1.f) * 31.f, xi = (dx + 1.f) * 31.f;
        float y0f = floorf(yi), x0f = floorf(xi);
        int y0 = (int)y0f, x0 = (int)x0f;
        float wy1 = yi - y0f, wx1 = xi - x0f;
        float bias = 0.f;
#pragma unroll
        for (int tt = 0; tt < 4; ++tt) {
            int iy = y0 + (tt >> 1), ix = x0 + (tt & 1);
            float wgt = ((tt >> 1) ? wy1 : 1.f - wy1) * ((tt & 1) ? wx1 : 1.f - wx1);
            if (iy >= 0 && iy <= 62 && ix >= 0 && ix <= 62)
                bias = fmaf(rp[iy * 63 + ix], wgt, bias);
        }
        float logit = fmaf(dot, SCALE_, bias);
        if (logit > m) {
            float corr = __expf(m - logit);
            l *= corr;
#pragma unroll
            for (int c = 0; c < 32; ++c) oacc[c] *= corr;
            m = logit;
        }
        float p = __expf(logit - m);
        l += p;
        const float* vr = vs + s * KSP;
#pragma unroll
        for (int c4 = 0; c4 < 8; ++c4) {
            float4 vv = *(const float4*)(vr + c4 * 4);
            oacc[c4 * 4 + 0] = fmaf(p, vv.x, oacc[c4 * 4 + 0]);
            oacc[c4 * 4 + 1] = fmaf(p, vv.y, oacc[c4 * 4 + 1]);
            oacc[c4 * 4 + 2] = fmaf(p, vv.z, oacc[c4 * 4 + 2]);
            oacc[c4 * 4 + 3] = fmaf(p, vv.w, oacc[c4 * 4 + 3]);
        }
    }

    // ---- merge the 4 wave-group partials ----
    ml[tid * 2 + 0] = m;
    ml[tid * 2 + 1] = l;
    __syncthreads();
    float m0 = ml[(t + 0) * 2], l0 = ml[(t + 0) * 2 + 1];
    float m1 = ml[(t + 256) * 2], l1 = ml[(t + 256) * 2 + 1];
    float m2 = ml[(t + 512) * 2], l2 = ml[(t + 512) * 2 + 1];
    float m3 = ml[(t + 768) * 2], l3 = ml[(t + 768) * 2 + 1];
    float mstar = fmaxf(fmaxf(m0, m1), fmaxf(m2, m3));
    float L = l0 * __expf(m0 - mstar) + l1 * __expf(m1 - mstar)
            + l2 * __expf(m2 - mstar) + l3 * __expf(m3 - mstar);
    float scale = __expf(m - mstar) / L;

    float* og = ao + ((size_t)(b * CC_ + h * HCH)) * HWSZ + qidx;
    float4* red = (float4*)rp;
#pragma unroll
    for (int cb = 0; cb < 8; ++cb) {
        __syncthreads();
        red[tid] = make_float4(oacc[cb * 4 + 0] * scale, oacc[cb * 4 + 1] * scale,
                               oacc[cb * 4 + 2] * scale, oacc[cb * 4 + 3] * scale);
        __syncthreads();
        if (w == 0) {
            float4 a = red[t], b4 = red[t + 256], c4 = red[t + 512], d4 = red[t + 768];
            float4 sm = make_float4(a.x + b4.x + c4.x + d4.x, a.y + b4.y + c4.y + d4.y,
                                    a.z + b4.z + c4.z + d4.z, a.w + b4.w + c4.w + d4.w);
            og[(size_t)(cb * 4 + 0) * HWSZ] = sm.x;
            og[(size_t)(cb * 4 + 1) * HWSZ] = sm.y;
            og[(size_t)(cb * 4 + 2) * HWSZ] = sm.z;
            og[(size_t)(cb * 4 + 3) * HWSZ] = sm.w;
        }
    }
}

extern "C" void kernel_launch(void* const* d_in, const int* in_sizes, int n_in,
                              void* d_out, int out_size, void* d_ws, size_t ws_size,
                              hipStream_t stream) {
    (void)in_sizes; (void)n_in; (void)out_size; (void)ws_size;
    const float* x   = (const float*)d_in[0];
    const float* Wq  = (const float*)d_in[1];
    const float* bq  = (const float*)d_in[2];
    const float* Wk  = (const float*)d_in[3];
    const float* bk  = (const float*)d_in[4];
    const float* Wv  = (const float*)d_in[5];
    const float* bv  = (const float*)d_in[6];
    const float* Wo  = (const float*)d_in[7];
    const float* bo  = (const float*)d_in[8];
    const float* dww = (const float*)d_in[9];
    const float* dwb = (const float*)d_in[10];
    const float* lng = (const float*)d_in[11];
    const float* lnb = (const float*)d_in[12];
    const float* pww = (const float*)d_in[13];
    const float* rpe = (const float*)d_in[14];
    float* out = (float*)d_out;

    float* ws   = (float*)d_ws;
    float* qbuf = ws;                       // 4*384*1024 = 1572864
    float* posb = qbuf + 1572864;           // 24*256*2   = 12288
    float* xsb  = posb + 12288;             // 4*384*256  = 393216
    float* kbuf = xsb + 393216;             // 393216
    float* vbuf = kbuf + 393216;            // 393216
    float* aout = vbuf + 393216;            // 1572864

    conv1x1_kernel<CC_><<<dim3(1, CC_ / 4, BB), 256, 0, stream>>>(Wq, bq, x, qbuf, HWSZ, CC_);
    offset_net_kernel<<<dim3(24), 256, 0, stream>>>(qbuf, dww, dwb, lng, lnb, pww, posb);
    sample_xs_kernel<<<dim3(NGC_, 24), 256, 0, stream>>>(x, posb, xsb);
    conv1x1_kernel<CC_><<<dim3(1, CC_ / 4, BB), 64, 0, stream>>>(Wk, bk, xsb, kbuf, NS_, CC_);
    conv1x1_kernel<CC_><<<dim3(1, CC_ / 4, BB), 64, 0, stream>>>(Wv, bv, xsb, vbuf, NS_, CC_);
    attn_kernel<<<dim3(4, BB * NHD), 1024, 0, stream>>>(qbuf, kbuf, vbuf, posb, rpe, aout);
    conv1x1_kernel<CC_><<<dim3(1, CC_ / 4, BB), 256, 0, stream>>>(Wo, bo, aout, out, HWSZ, CC_);
}

// Round 3
// 234.961 us; speedup vs baseline: 1.7877x; 1.4549x over previous
//
#include <hip/hip_runtime.h>
#include <hip/hip_bf16.h>

#define BB 4
#define CC_ 384
#define HH 32
#define WW 32
#define HWSZ 1024
#define NHD 12
#define HCH 32
#define GG 6
#define NGC_ 64
#define GHD 2
#define HK_ 16
#define WK_ 16
#define NS_ 256
#define RPEW 63
#define SCALE_ 0.17677669529663687f

// ---------------- K1/K4/K6: 1x1 conv / batched GEMM ----------------
template<int CIN>
__global__ void conv1x1_kernel(const float* __restrict__ W, const float* __restrict__ bias,
                               const float* __restrict__ X, float* __restrict__ Y,
                               int N, int OC)
{
    const int otile = blockIdx.y * 4;
    const int b = blockIdx.z;
    const int n4 = (blockIdx.x * blockDim.x + threadIdx.x) * 4;
    const float* Xb = X + (size_t)b * CIN * N + n4;
    const float* Wr = W + (size_t)otile * CIN;

    float acc[4][4];
#pragma unroll
    for (int j = 0; j < 4; ++j)
#pragma unroll
        for (int i = 0; i < 4; ++i) acc[j][i] = 0.f;

    for (int c = 0; c < CIN; ++c) {
        float4 xv = *(const float4*)(Xb + (size_t)c * N);
#pragma unroll
        for (int j = 0; j < 4; ++j) {
            float w = Wr[j * CIN + c];
            acc[j][0] = fmaf(w, xv.x, acc[j][0]);
            acc[j][1] = fmaf(w, xv.y, acc[j][1]);
            acc[j][2] = fmaf(w, xv.z, acc[j][2]);
            acc[j][3] = fmaf(w, xv.w, acc[j][3]);
        }
    }
#pragma unroll
    for (int j = 0; j < 4; ++j) {
        int o = otile + j;
        float bv = bias[o];
        float4 r = make_float4(acc[j][0] + bv, acc[j][1] + bv, acc[j][2] + bv, acc[j][3] + bv);
        *(float4*)(Y + ((size_t)(b * OC + o)) * N + n4) = r;
    }
}

// ---------------- K2a: depthwise conv 5x5 stride 2 ----------------
// grid: (64 channels, 24 bg), block 256 = 16x16 output positions
__global__ void offset_dw_kernel(const float* __restrict__ qb, const float* __restrict__ dww,
                                 const float* __restrict__ dwb, float* __restrict__ cobuf)
{
    __shared__ float img[HWSZ];
    const int c = blockIdx.x, bg = blockIdx.y;
    const int b = bg / GG, g = bg - b * GG;
    const int tid = threadIdx.x;
    const float* src = qb + ((size_t)(b * CC_ + g * NGC_ + c)) * HWSZ;
#pragma unroll
    for (int e = tid; e < HWSZ; e += 256) img[e] = src[e];
    __syncthreads();
    const int oy = tid >> 4, ox = tid & 15;
    float s = dwb[c];
    const float* wf = dww + c * 25;
    const int iy0 = oy * 2 - 2, ix0 = ox * 2 - 2;
#pragma unroll
    for (int ky = 0; ky < 5; ++ky) {
        int iy = iy0 + ky;
        if (iy < 0 || iy > 31) continue;
#pragma unroll
        for (int kx = 0; kx < 5; ++kx) {
            int ix = ix0 + kx;
            if (ix < 0 || ix > 31) continue;
            s = fmaf(img[iy * 32 + ix], wf[ky * 5 + kx], s);
        }
    }
    cobuf[((size_t)(bg * NGC_ + c)) * 256 + tid] = s;
}

// ---------------- K2b: LN + GELU + pwconv + tanh -> pos ----------------
// grid: 24 bg, block 256 = positions; per-thread 64-channel column in regs
__global__ void offset_fin_kernel(const float* __restrict__ cobuf, const float* __restrict__ lng,
                                  const float* __restrict__ lnb, const float* __restrict__ pww,
                                  float* __restrict__ posb)
{
    const int bg = blockIdx.x;
    const int tid = threadIdx.x;
    const int oy = tid >> 4, ox = tid & 15;
    const float* base = cobuf + (size_t)bg * NGC_ * 256 + tid;
    float v[NGC_];
    float mu = 0.f;
#pragma unroll
    for (int c = 0; c < NGC_; ++c) { v[c] = base[(size_t)c * 256]; mu += v[c]; }
    mu *= (1.f / 64.f);
    float var = 0.f;
#pragma unroll
    for (int c = 0; c < NGC_; ++c) { float d = v[c] - mu; var += d * d; }
    var *= (1.f / 64.f);
    float rstd = rsqrtf(var + 1e-5f);
    float o0 = 0.f, o1 = 0.f;
#pragma unroll
    for (int c = 0; c < NGC_; ++c) {
        float t = (v[c] - mu) * rstd * lng[c] + lnb[c];
        float gv = 0.5f * t * (1.f + erff(t * 0.70710678118654752f));
        o0 = fmaf(pww[c], gv, o0);
        o1 = fmaf(pww[64 + c], gv, o1);
    }
    float py = tanhf(o0) * (2.f / 15.f) + ((0.5f + (float)oy) * (1.f / 15.f)) * 2.f - 1.f;
    float px = tanhf(o1) * (2.f / 15.f) + ((0.5f + (float)ox) * (1.f / 15.f)) * 2.f - 1.f;
    posb[bg * 512 + tid * 2 + 0] = py;
    posb[bg * 512 + tid * 2 + 1] = px;
}

// ---------------- K3: bilinear KV sampling ----------------
__global__ void sample_xs_kernel(const float* __restrict__ x, const float* __restrict__ posb,
                                 float* __restrict__ xsb)
{
    const int cc = blockIdx.x, bg = blockIdx.y;
    const int b = bg / GG, g = bg - b * GG;
    const int s = threadIdx.x;
    float py = posb[bg * 512 + s * 2 + 0];
    float px = posb[bg * 512 + s * 2 + 1];
    float xi = (px + 1.f) * 0.5f * 31.f;
    float yi = (py + 1.f) * 0.5f * 31.f;
    float x0f = floorf(xi), y0f = floorf(yi);
    int x0 = (int)x0f, y0 = (int)y0f;
    float wx1 = xi - x0f, wy1 = yi - y0f;
    const float* img = x + ((size_t)(b * CC_ + g * NGC_ + cc)) * HWSZ;
    float acc = 0.f;
#pragma unroll
    for (int t = 0; t < 4; ++t) {
        int iy = y0 + (t >> 1), ix = x0 + (t & 1);
        float w = ((t >> 1) ? wy1 : 1.f - wy1) * ((t & 1) ? wx1 : 1.f - wx1);
        if (iy >= 0 && iy <= 31 && ix >= 0 && ix <= 31)
            acc = fmaf(img[iy * 32 + ix], w, acc);
    }
    xsb[((size_t)(b * CC_ + g * NGC_ + cc)) * NS_ + s] = acc;
}

// ---------------- K5: fused attention, in-block sample-split ----------------
#define KSP 36
__launch_bounds__(1024, 4)
__global__ void attn_kernel(const float* __restrict__ qb, const float* __restrict__ kb,
                            const float* __restrict__ vb, const float* __restrict__ posb,
                            const float* __restrict__ rpe, float* __restrict__ ao)
{
    __shared__ float ks[256 * KSP];
    __shared__ float vs[256 * KSP];
    __shared__ float rp[4096];
    __shared__ float ps[512];
    __shared__ float ml[2048];
    const int bh = blockIdx.y;
    const int b = bh / NHD, h = bh - b * NHD;
    const int bg = b * GG + (h >> 1);
    const int tid = threadIdx.x;
    const int w = tid >> 8, t = tid & 255;

    const float* kg = kb + (size_t)bh * (HCH * NS_);
    const float* vg = vb + (size_t)bh * (HCH * NS_);
    for (int e = tid; e < HCH * NS_; e += 1024) {
        int c = e >> 8, s = e & 255;
        ks[s * KSP + c] = kg[e];
        vs[s * KSP + c] = vg[e];
    }
    for (int e = tid; e < RPEW * RPEW; e += 1024) rp[e] = rpe[(size_t)h * (RPEW * RPEW) + e];
    if (tid < 512) ps[tid] = posb[bg * 512 + tid];
    __syncthreads();

    const int qidx = blockIdx.x * 256 + t;
    const int row = qidx >> 5, col = qidx & 31;
    const float gyq = (float)row * (2.f / 31.f) - 1.f;
    const float gxq = (float)col * (2.f / 31.f) - 1.f;

    float qf[32];
    const float* qg = qb + ((size_t)(b * CC_ + h * HCH)) * HWSZ + qidx;
#pragma unroll
    for (int c = 0; c < 32; ++c) qf[c] = qg[(size_t)c * HWSZ];

    float m = -3.0e38f, l = 0.f;
    float oacc[32];
#pragma unroll
    for (int c = 0; c < 32; ++c) oacc[c] = 0.f;

    const int s0 = w * 64;
    for (int s = s0; s < s0 + 64; ++s) {
        const float* kr = ks + s * KSP;
        float d0 = 0.f, d1 = 0.f, d2 = 0.f, d3 = 0.f;
#pragma unroll
        for (int c4 = 0; c4 < 2; ++c4) {
            float4 ka = *(const float4*)(kr + c4 * 16 + 0);
            float4 kb4 = *(const float4*)(kr + c4 * 16 + 4);
            float4 kc = *(const float4*)(kr + c4 * 16 + 8);
            float4 kd = *(const float4*)(kr + c4 * 16 + 12);
            int o = c4 * 16;
            d0 = fmaf(qf[o + 0], ka.x, d0); d0 = fmaf(qf[o + 1], ka.y, d0);
            d0 = fmaf(qf[o + 2], ka.z, d0); d0 = fmaf(qf[o + 3], ka.w, d0);
            d1 = fmaf(qf[o + 4], kb4.x, d1); d1 = fmaf(qf[o + 5], kb4.y, d1);
            d1 = fmaf(qf[o + 6], kb4.z, d1); d1 = fmaf(qf[o + 7], kb4.w, d1);
            d2 = fmaf(qf[o + 8], kc.x, d2); d2 = fmaf(qf[o + 9], kc.y, d2);
            d2 = fmaf(qf[o + 10], kc.z, d2); d2 = fmaf(qf[o + 11], kc.w, d2);
            d3 = fmaf(qf[o + 12], kd.x, d3); d3 = fmaf(qf[o + 13], kd.y, d3);
            d3 = fmaf(qf[o + 14], kd.z, d3); d3 = fmaf(qf[o + 15], kd.w, d3);
        }
        float dot = (d0 + d1) + (d2 + d3);

        float py = ps[s * 2 + 0], px = ps[s * 2 + 1];
        float dy = (gyq - py) * 0.5f, dx = (gxq - px) * 0.5f;
        float yi = (dy + 1.f) * 31.f, xi = (dx + 1.f) * 31.f;
        float y0f = floorf(yi), x0f = floorf(xi);
        int y0 = (int)y0f, x0 = (int)x0f;
        float wy1 = yi - y0f, wx1 = xi - x0f;
        float bias = 0.f;
#pragma unroll
        for (int tt = 0; tt < 4; ++tt) {
            int iy = y0 + (tt >> 1), ix = x0 + (tt & 1);
            float wgt = ((tt >> 1) ? wy1 : 1.f - wy1) * ((tt & 1) ? wx1 : 1.f - wx1);
            if (iy >= 0 && iy <= 62 && ix >= 0 && ix <= 62)
                bias = fmaf(rp[iy * 63 + ix], wgt, bias);
        }
        float logit = fmaf(dot, SCALE_, bias);
        if (logit > m) {
            float corr = __expf(m - logit);
            l *= corr;
#pragma unroll
            for (int c = 0; c < 32; ++c) oacc[c] *= corr;
            m = logit;
        }
        float p = __expf(logit - m);
        l += p;
        const float* vr = vs + s * KSP;
#pragma unroll
        for (int c4 = 0; c4 < 8; ++c4) {
            float4 vv = *(const float4*)(vr + c4 * 4);
            oacc[c4 * 4 + 0] = fmaf(p, vv.x, oacc[c4 * 4 + 0]);
            oacc[c4 * 4 + 1] = fmaf(p, vv.y, oacc[c4 * 4 + 1]);
            oacc[c4 * 4 + 2] = fmaf(p, vv.z, oacc[c4 * 4 + 2]);
            oacc[c4 * 4 + 3] = fmaf(p, vv.w, oacc[c4 * 4 + 3]);
        }
    }

    ml[tid * 2 + 0] = m;
    ml[tid * 2 + 1] = l;
    __syncthreads();
    float m0 = ml[(t + 0) * 2], l0 = ml[(t + 0) * 2 + 1];
    float m1 = ml[(t + 256) * 2], l1 = ml[(t + 256) * 2 + 1];
    float m2 = ml[(t + 512) * 2], l2 = ml[(t + 512) * 2 + 1];
    float m3 = ml[(t + 768) * 2], l3 = ml[(t + 768) * 2 + 1];
    float mstar = fmaxf(fmaxf(m0, m1), fmaxf(m2, m3));
    float L = l0 * __expf(m0 - mstar) + l1 * __expf(m1 - mstar)
            + l2 * __expf(m2 - mstar) + l3 * __expf(m3 - mstar);
    float scale = __expf(m - mstar) / L;

    float* og = ao + ((size_t)(b * CC_ + h * HCH)) * HWSZ + qidx;
    float4* red = (float4*)rp;
#pragma unroll
    for (int cb = 0; cb < 8; ++cb) {
        __syncthreads();
        red[tid] = make_float4(oacc[cb * 4 + 0] * scale, oacc[cb * 4 + 1] * scale,
                               oacc[cb * 4 + 2] * scale, oacc[cb * 4 + 3] * scale);
        __syncthreads();
        if (w == 0) {
            float4 a = red[t], b4 = red[t + 256], c4 = red[t + 512], d4 = red[t + 768];
            float4 sm = make_float4(a.x + b4.x + c4.x + d4.x, a.y + b4.y + c4.y + d4.y,
                                    a.z + b4.z + c4.z + d4.z, a.w + b4.w + c4.w + d4.w);
            og[(size_t)(cb * 4 + 0) * HWSZ] = sm.x;
            og[(size_t)(cb * 4 + 1) * HWSZ] = sm.y;
            og[(size_t)(cb * 4 + 2) * HWSZ] = sm.z;
            og[(size_t)(cb * 4 + 3) * HWSZ] = sm.w;
        }
    }
}

extern "C" void kernel_launch(void* const* d_in, const int* in_sizes, int n_in,
                              void* d_out, int out_size, void* d_ws, size_t ws_size,
                              hipStream_t stream) {
    (void)in_sizes; (void)n_in; (void)out_size; (void)ws_size;
    const float* x   = (const float*)d_in[0];
    const float* Wq  = (const float*)d_in[1];
    const float* bq  = (const float*)d_in[2];
    const float* Wk  = (const float*)d_in[3];
    const float* bk  = (const float*)d_in[4];
    const float* Wv  = (const float*)d_in[5];
    const float* bv  = (const float*)d_in[6];
    const float* Wo  = (const float*)d_in[7];
    const float* bo  = (const float*)d_in[8];
    const float* dww = (const float*)d_in[9];
    const float* dwb = (const float*)d_in[10];
    const float* lng = (const float*)d_in[11];
    const float* lnb = (const float*)d_in[12];
    const float* pww = (const float*)d_in[13];
    const float* rpe = (const float*)d_in[14];
    float* out = (float*)d_out;

    float* ws   = (float*)d_ws;
    float* qbuf = ws;                       // 1572864
    float* posb = qbuf + 1572864;           // 12288
    float* xsb  = posb + 12288;             // 393216
    float* kbuf = xsb + 393216;             // 393216
    float* vbuf = kbuf + 393216;            // 393216
    float* aout = vbuf + 393216;            // 1572864
    float* cobuf = aout;                    // 393216, dead before attn writes aout

    conv1x1_kernel<CC_><<<dim3(1, CC_ / 4, BB), 256, 0, stream>>>(Wq, bq, x, qbuf, HWSZ, CC_);
    offset_dw_kernel<<<dim3(NGC_, 24), 256, 0, stream>>>(qbuf, dww, dwb, cobuf);
    offset_fin_kernel<<<dim3(24), 256, 0, stream>>>(cobuf, lng, lnb, pww, posb);
    sample_xs_kernel<<<dim3(NGC_, 24), 256, 0, stream>>>(x, posb, xsb);
    conv1x1_kernel<CC_><<<dim3(1, CC_ / 4, BB), 64, 0, stream>>>(Wk, bk, xsb, kbuf, NS_, CC_);
    conv1x1_kernel<CC_><<<dim3(1, CC_ / 4, BB), 64, 0, stream>>>(Wv, bv, xsb, vbuf, NS_, CC_);
    attn_kernel<<<dim3(4, BB * NHD), 1024, 0, stream>>>(qbuf, kbuf, vbuf, posb, rpe, aout);
    conv1x1_kernel<CC_><<<dim3(1, CC_ / 4, BB), 256, 0, stream>>>(Wo, bo, aout, out, HWSZ, CC_);
}